// Round 2
// baseline (426.214 us; speedup 1.0000x reference)
//
#include <hip/hip_runtime.h>
#include <cmath>
#include <cstdint>

#define NB 32
#define NI 512
#define NT 4096
#define NSTEPS (NT - 2)   // 4094

// ---------------------------------------------------------------------------
// JAX threefry2x32 (20 rounds), matches jax/_src/prng.py exactly.
// ---------------------------------------------------------------------------
__device__ __forceinline__ uint32_t rotl32(uint32_t v, unsigned d) {
  return (v << d) | (v >> (32u - d));
}

__device__ __forceinline__ void threefry2x32(uint32_t k0, uint32_t k1,
                                             uint32_t& x0, uint32_t& x1) {
  const uint32_t k2 = k0 ^ k1 ^ 0x1BD11BDAu;
  x0 += k0; x1 += k1;
#define TF_R(rot) { x0 += x1; x1 = rotl32(x1, rot); x1 ^= x0; }
  TF_R(13) TF_R(15) TF_R(26) TF_R(6)
  x0 += k1; x1 += k2 + 1u;
  TF_R(17) TF_R(29) TF_R(16) TF_R(24)
  x0 += k2; x1 += k0 + 2u;
  TF_R(13) TF_R(15) TF_R(26) TF_R(6)
  x0 += k0; x1 += k1 + 3u;
  TF_R(17) TF_R(29) TF_R(16) TF_R(24)
  x0 += k1; x1 += k2 + 4u;
  TF_R(13) TF_R(15) TF_R(26) TF_R(6)
  x0 += k2; x1 += k0 + 5u;
#undef TF_R
}

// uniform(minval=tiny,maxval=1) -> gumbel, f32 rounding after each log
// (emulated via correctly-rounded double log). Verified bit-exact (round 1).
__device__ __forceinline__ float gumbel_from_bits(uint32_t bits) {
  uint32_t fb = (bits >> 9) | 0x3F800000u;
  float f = __uint_as_float(fb) - 1.0f;          // [0, 1)
  float u = fmaxf(f, __FLT_MIN__);               // jnp.finfo(f32).tiny
  float lg = (float)log((double)u);
  return -(float)log((double)(-lg));
}

// ---------------------------------------------------------------------------
// K1: per (t,b): key_t = threefry((0,42),(0,t)) [partitionable split], then
// 3 gumbels (element e=3b+j -> y0^y1 of threefry(key_t,(0,e))), then argmax
// over the two possible logit rows:
//   row A (generic):            [LP, LS, LP]
//   row B (state (p2,p1)=(1,2)): [-inf, LB1, LB2]
// Stores u32 = sA | (sB<<4) per (b,t) with AGENT scope (cross-XCD visible).
// ---------------------------------------------------------------------------
__global__ void k_sab(uint32_t* __restrict__ sab32,
                      float LP, float LS, float LB1, float LB2) {
  int t = blockIdx.x * blockDim.x + threadIdx.x;
  int b = blockIdx.y;
  if (t >= NSTEPS) return;
  uint32_t k0 = 0u, k1 = (uint32_t)t;
  threefry2x32(0u, 42u, k0, k1);                 // key_t
  float g[3];
#pragma unroll
  for (int j = 0; j < 3; ++j) {
    uint32_t x0 = 0u, x1 = (uint32_t)(3 * b + j);
    threefry2x32(k0, k1, x0, x1);
    g[j] = gumbel_from_bits(x0 ^ x1);
  }
  float vA0 = LP + g[0], vA1 = LS + g[1], vA2 = LP + g[2];
  int sA = 0; float m = vA0;
  if (vA1 > m) { m = vA1; sA = 1; }
  if (vA2 > m) { sA = 2; }
  int sB = (LB2 + g[2] > LB1 + g[1]) ? 2 : 1;    // j=0 logit is -inf
  uint32_t v = (uint32_t)(sA | (sB << 4));
  __hip_atomic_store(&sab32[(size_t)b * NT + t], v,
                     __ATOMIC_RELAXED, __HIP_MEMORY_SCOPE_AGENT);
}

// ---------------------------------------------------------------------------
// K2: serial Markov chain, one lane per batch row. Reads sab32 with AGENT
// scope (16-batched for latency), writes packed m words with AGENT scope.
// m[b][0]=1, m[b][tt]=s_{tt-1} for tt in [1,4095), m[b][4095]=1.
// ---------------------------------------------------------------------------
__global__ void k_chain(uint32_t* __restrict__ sab32, uint32_t* __restrict__ mword) {
  int b = threadIdx.x;
  if (b >= NB) return;
  uint32_t* src = sab32 + (size_t)b * NT;
  uint32_t* dst = mword + (size_t)b * (NT / 4);
  int p1 = 1, spec = 0;
  uint32_t outw = 1u;                            // byte0 = m[0] = 1
  for (int c = 0; c < 256; ++c) {                // 256 chunks of 16 steps
    uint32_t e[16];
    int base = c * 16;
#pragma unroll
    for (int k = 0; k < 16; ++k) {
      int t = base + k;
      e[k] = (t < NSTEPS)
           ? __hip_atomic_load(&src[t], __ATOMIC_RELAXED, __HIP_MEMORY_SCOPE_AGENT)
           : 0u;
    }
#pragma unroll
    for (int k = 0; k < 16; ++k) {
      int t = base + k;
      if (t >= NSTEPS) break;
      uint32_t w = e[k];
      int s = (int)((spec ? (w >> 4) : w) & 0xFu);
      int tt = t + 1;
      outw |= (uint32_t)s << ((tt & 3) * 8);
      if ((tt & 3) == 3) {
        __hip_atomic_store(&dst[tt >> 2], outw,
                           __ATOMIC_RELAXED, __HIP_MEMORY_SCOPE_AGENT);
        outw = 0u;
      }
      spec = (p1 == 1) & (s == 2);
      p1 = s;
    }
  }
  // last step was tt=4094 (lane 2); add m[4095]=1 and flush word 1023
  outw |= 1u << 24;
  __hip_atomic_store(&dst[(NT / 4) - 1], outw,
                     __ATOMIC_RELAXED, __HIP_MEMORY_SCOPE_AGENT);
}

// ---------------------------------------------------------------------------
// K3: gather out[b,i,t] = x[b,i, m[b,t] + t - 1], float4 stores over t.
// m words read with AGENT scope (values produced on another XCD's L2).
// ---------------------------------------------------------------------------
__global__ void k_gather(const float* __restrict__ x, uint32_t* __restrict__ mword,
                         float* __restrict__ out) {
  const int QUADS = NB * NI * (NT / 4);          // 16,777,216
  int stride = gridDim.x * blockDim.x;
  for (int q = blockIdx.x * blockDim.x + threadIdx.x; q < QUADS; q += stride) {
    int b   = q >> 19;                           // NI * NT/4 = 2^19
    int rem = q & ((1 << 19) - 1);
    int i   = rem >> 10;                         // NT/4 = 1024
    int t   = (rem & 1023) << 2;
    uint32_t mw = __hip_atomic_load(&mword[((size_t)b << 10) + (t >> 2)],
                                    __ATOMIC_RELAXED, __HIP_MEMORY_SCOPE_AGENT);
    const float* xb = x + (((size_t)b * NI + i) << 12);
    float4 o;
    o.x = xb[(int)( mw        & 0xFFu) + t + 0 - 1];
    o.y = xb[(int)((mw >>  8) & 0xFFu) + t + 1 - 1];
    o.z = xb[(int)((mw >> 16) & 0xFFu) + t + 2 - 1];
    o.w = xb[(int)((mw >> 24) & 0xFFu) + t + 3 - 1];
    *(float4*)(out + (((size_t)b * NI + i) << 12) + t) = o;
  }
}

// ---------------------------------------------------------------------------
extern "C" void kernel_launch(void* const* d_in, const int* in_sizes, int n_in,
                              void* d_out, int out_size, void* d_ws, size_t ws_size,
                              hipStream_t stream) {
  const float* x = (const float*)d_in[0];
  float* out = (float*)d_out;

  uint8_t* ws = (uint8_t*)d_ws;
  uint32_t* sab32 = (uint32_t*)ws;               // 32*4096*4 = 524288 B
  uint32_t* mword = (uint32_t*)(ws + 524288);    // 32*1024*4 = 131072 B

  const double pd = 0.1, sd = 1.0 - 2.0 * 0.1;
  const float pf = (float)pd, sf = (float)sd;
  const float b1 = (float)(sd / (pd + sd));
  const float b2 = (float)(pd / (pd + sd));
  const float LP  = (float)log((double)pf);
  const float LS  = (float)log((double)sf);
  const float LB1 = (float)log((double)b1);
  const float LB2 = (float)log((double)b2);

  dim3 g1((NSTEPS + 255) / 256, NB);
  k_sab<<<g1, 256, 0, stream>>>(sab32, LP, LS, LB1, LB2);
  k_chain<<<1, 64, 0, stream>>>(sab32, mword);
  k_gather<<<4096, 256, 0, stream>>>(x, mword, out);
}

// Round 3
// 136.169 us; speedup vs baseline: 3.1300x; 3.1300x over previous
//
#include <hip/hip_runtime.h>
#include <cmath>
#include <cstdint>

#define NB 32
#define NI 512
#define NT 4096
#define NSTEPS (NT - 2)   // 4094
#define THR 512           // threads per k_mask block
#define SPT 8             // steps per thread (512*8 = 4096 >= 4094)

// ---------------------------------------------------------------------------
// JAX threefry2x32 (20 rounds), matches jax/_src/prng.py exactly.
// Verified bit-exact on hardware (rounds 1-2: absmax 0.0).
// ---------------------------------------------------------------------------
__device__ __forceinline__ uint32_t rotl32(uint32_t v, unsigned d) {
  return (v << d) | (v >> (32u - d));
}

__device__ __forceinline__ void threefry2x32(uint32_t k0, uint32_t k1,
                                             uint32_t& x0, uint32_t& x1) {
  const uint32_t k2 = k0 ^ k1 ^ 0x1BD11BDAu;
  x0 += k0; x1 += k1;
#define TF_R(rot) { x0 += x1; x1 = rotl32(x1, rot); x1 ^= x0; }
  TF_R(13) TF_R(15) TF_R(26) TF_R(6)
  x0 += k1; x1 += k2 + 1u;
  TF_R(17) TF_R(29) TF_R(16) TF_R(24)
  x0 += k2; x1 += k0 + 2u;
  TF_R(13) TF_R(15) TF_R(26) TF_R(6)
  x0 += k0; x1 += k1 + 3u;
  TF_R(17) TF_R(29) TF_R(16) TF_R(24)
  x0 += k1; x1 += k2 + 4u;
  TF_R(13) TF_R(15) TF_R(26) TF_R(6)
  x0 += k2; x1 += k0 + 5u;
#undef TF_R
}

// uniform(minval=tiny,maxval=1) -> gumbel, f32 rounding after each log
// (emulated via correctly-rounded double log). Verified bit-exact.
__device__ __forceinline__ float gumbel_from_bits(uint32_t bits) {
  uint32_t fb = (bits >> 9) | 0x3F800000u;
  float f = __uint_as_float(fb) - 1.0f;          // [0, 1)
  float u = fmaxf(f, __FLT_MIN__);               // jnp.finfo(f32).tiny
  float lg = (float)log((double)u);
  return -(float)log((double)(-lg));
}

// ---------------------------------------------------------------------------
// 4-state chain encoding: 0:(p1=0) 1:(p1=1) 2:(p1=2,spec=0) 3:(p1=2,spec=1).
// Step with samples (sA generic row, sB special row):
//   s  = (st==3) ? sB : sA
//   st'= (st==1 && s==2) ? 3 : s
// Map over 4 states packed 2 bits/state in a u32 (low 8 bits).
// ---------------------------------------------------------------------------
__device__ __forceinline__ uint32_t comp_map(uint32_t a, uint32_t b) {
  // apply a, then b
  uint32_t r = 0;
#pragma unroll
  for (int st = 0; st < 4; ++st) {
    uint32_t as = (a >> (2 * st)) & 3u;
    uint32_t bs = (b >> (2 * as)) & 3u;
    r |= bs << (2 * st);
  }
  return r;
}

// ---------------------------------------------------------------------------
// K1: one block per batch. Phase 1: per-thread (sA,sB) for SPT steps
// (fused threefry split/random_bits/gumbel/argmax). Phase 2: 4-state map
// scan across the block. Phase 3: replay + write m bytes to LDS, then
// cooperative AGENT-scope word stores (cross-XCD visibility for k_gather).
// ---------------------------------------------------------------------------
__global__ void __launch_bounds__(THR) k_mask(uint32_t* __restrict__ mword,
                                              float LP, float LS,
                                              float LB1, float LB2) {
  const int b = blockIdx.x;
  const int tid = threadIdx.x;

  __shared__ uint32_t smap[THR];
  __shared__ uint8_t lds_m[NT];

  // ---- Phase 1: compute sA/sB for my SPT steps, pack nibbles ----
  uint32_t packA = 0, packB = 0;
#pragma unroll
  for (int k = 0; k < SPT; ++k) {
    int t = tid * SPT + k;
    if (t >= NSTEPS) break;
    // key_t = threefry((0,42),(0,t))  [partitionable split]
    uint32_t k0 = 0u, k1 = (uint32_t)t;
    threefry2x32(0u, 42u, k0, k1);
    float g[3];
#pragma unroll
    for (int j = 0; j < 3; ++j) {
      uint32_t x0 = 0u, x1 = (uint32_t)(3 * b + j);
      threefry2x32(k0, k1, x0, x1);
      g[j] = gumbel_from_bits(x0 ^ x1);
    }
    float vA0 = LP + g[0], vA1 = LS + g[1], vA2 = LP + g[2];
    int sA = 0; float m = vA0;
    if (vA1 > m) { m = vA1; sA = 1; }
    if (vA2 > m) { sA = 2; }
    int sB = (LB2 + g[2] > LB1 + g[1]) ? 2 : 1;  // j=0 logit is -inf
    packA |= (uint32_t)sA << (4 * k);
    packB |= (uint32_t)sB << (4 * k);
  }

  // ---- Phase 2: build my chunk map, scan across block ----
  uint32_t cmap = 0xE4u;                         // identity: 3,2,1,0 -> 11 10 01 00
  {
    uint32_t st0 = 0, st1 = 1, st2 = 2, st3 = 3;
#pragma unroll
    for (int k = 0; k < SPT; ++k) {
      int t = tid * SPT + k;
      if (t >= NSTEPS) break;
      uint32_t sA = (packA >> (4 * k)) & 0xFu;
      uint32_t sB = (packB >> (4 * k)) & 0xFu;
#define STEP(st) { uint32_t s = (st == 3u) ? sB : sA; st = (st == 1u && s == 2u) ? 3u : s; }
      STEP(st0) STEP(st1) STEP(st2) STEP(st3)
#undef STEP
    }
    cmap = st0 | (st1 << 2) | (st2 << 4) | (st3 << 6);
  }
  smap[tid] = cmap;
  __syncthreads();
  for (int d = 1; d < THR; d <<= 1) {
    uint32_t prev = (tid >= d) ? smap[tid - d] : 0u;
    __syncthreads();
    if (tid >= d) smap[tid] = comp_map(prev, smap[tid]);
    __syncthreads();
  }
  // entry state for my chunk: prefix of chunks [0, tid) applied to st0=1
  uint32_t st = (tid == 0) ? 1u : ((smap[tid - 1] >> 2) & 3u);

  // ---- Phase 3: replay, write m bytes ----
#pragma unroll
  for (int k = 0; k < SPT; ++k) {
    int t = tid * SPT + k;
    if (t >= NSTEPS) break;
    uint32_t sA = (packA >> (4 * k)) & 0xFu;
    uint32_t sB = (packB >> (4 * k)) & 0xFu;
    uint32_t s = (st == 3u) ? sB : sA;
    st = (st == 1u && s == 2u) ? 3u : s;
    lds_m[t + 1] = (uint8_t)s;
  }
  if (tid == 0) lds_m[0] = 1;
  if (tid == THR - 1) lds_m[NT - 1] = 1;
  __syncthreads();

  // ---- cooperative AGENT-scope stores of packed words ----
  const uint32_t* wsrc = (const uint32_t*)lds_m;
  uint32_t* dst = mword + (size_t)b * (NT / 4);
#pragma unroll
  for (int r = 0; r < (NT / 4) / THR; ++r) {
    int w = r * THR + tid;
    __hip_atomic_store(&dst[w], wsrc[w],
                       __ATOMIC_RELAXED, __HIP_MEMORY_SCOPE_AGENT);
  }
}

// ---------------------------------------------------------------------------
// K2: gather out[b,i,t] = x[b,i, m[b,t] + t - 1], float4 stores over t.
// m words read with AGENT scope (produced on other XCDs).
// ---------------------------------------------------------------------------
__global__ void k_gather(const float* __restrict__ x, uint32_t* __restrict__ mword,
                         float* __restrict__ out) {
  const int QUADS = NB * NI * (NT / 4);          // 16,777,216
  int stride = gridDim.x * blockDim.x;
  for (int q = blockIdx.x * blockDim.x + threadIdx.x; q < QUADS; q += stride) {
    int b   = q >> 19;                           // NI * NT/4 = 2^19
    int rem = q & ((1 << 19) - 1);
    int i   = rem >> 10;                         // NT/4 = 1024
    int t   = (rem & 1023) << 2;
    uint32_t mw = __hip_atomic_load(&mword[((size_t)b << 10) + (t >> 2)],
                                    __ATOMIC_RELAXED, __HIP_MEMORY_SCOPE_AGENT);
    const float* xb = x + (((size_t)b * NI + i) << 12);
    float4 o;
    o.x = xb[(int)( mw        & 0xFFu) + t + 0 - 1];
    o.y = xb[(int)((mw >>  8) & 0xFFu) + t + 1 - 1];
    o.z = xb[(int)((mw >> 16) & 0xFFu) + t + 2 - 1];
    o.w = xb[(int)((mw >> 24) & 0xFFu) + t + 3 - 1];
    *(float4*)(out + (((size_t)b * NI + i) << 12) + t) = o;
  }
}

// ---------------------------------------------------------------------------
extern "C" void kernel_launch(void* const* d_in, const int* in_sizes, int n_in,
                              void* d_out, int out_size, void* d_ws, size_t ws_size,
                              hipStream_t stream) {
  const float* x = (const float*)d_in[0];
  float* out = (float*)d_out;

  uint32_t* mword = (uint32_t*)d_ws;             // 32*1024*4 = 131072 B

  const double pd = 0.1, sd = 1.0 - 2.0 * 0.1;
  const float pf = (float)pd, sf = (float)sd;
  const float b1 = (float)(sd / (pd + sd));
  const float b2 = (float)(pd / (pd + sd));
  const float LP  = (float)log((double)pf);
  const float LS  = (float)log((double)sf);
  const float LB1 = (float)log((double)b1);
  const float LB2 = (float)log((double)b2);

  k_mask<<<NB, THR, 0, stream>>>(mword, LP, LS, LB1, LB2);
  k_gather<<<4096, 256, 0, stream>>>(x, mword, out);
}

// Round 4
// 120.685 us; speedup vs baseline: 3.5316x; 1.1283x over previous
//
#include <hip/hip_runtime.h>
#include <cmath>
#include <cstdint>

#define NB 32
#define NI 512
#define NT 4096
#define NSTEPS (NT - 2)   // 4094
#define THR 512           // threads per k_scan block
#define SPT 8             // steps per thread (512*8 = 4096 >= 4094)

// ---------------------------------------------------------------------------
// JAX threefry2x32 (20 rounds), matches jax/_src/prng.py exactly.
// Verified bit-exact on hardware (rounds 1-3: absmax 0.0).
// ---------------------------------------------------------------------------
__device__ __forceinline__ uint32_t rotl32(uint32_t v, unsigned d) {
  return (v << d) | (v >> (32u - d));
}

__device__ __forceinline__ void threefry2x32(uint32_t k0, uint32_t k1,
                                             uint32_t& x0, uint32_t& x1) {
  const uint32_t k2 = k0 ^ k1 ^ 0x1BD11BDAu;
  x0 += k0; x1 += k1;
#define TF_R(rot) { x0 += x1; x1 = rotl32(x1, rot); x1 ^= x0; }
  TF_R(13) TF_R(15) TF_R(26) TF_R(6)
  x0 += k1; x1 += k2 + 1u;
  TF_R(17) TF_R(29) TF_R(16) TF_R(24)
  x0 += k2; x1 += k0 + 2u;
  TF_R(13) TF_R(15) TF_R(26) TF_R(6)
  x0 += k0; x1 += k1 + 3u;
  TF_R(17) TF_R(29) TF_R(16) TF_R(24)
  x0 += k1; x1 += k2 + 4u;
  TF_R(13) TF_R(15) TF_R(26) TF_R(6)
  x0 += k2; x1 += k0 + 5u;
#undef TF_R
}

// uniform(minval=tiny,maxval=1) -> gumbel, f32 rounding after each log
// (emulated via correctly-rounded double log). Verified bit-exact.
__device__ __forceinline__ float gumbel_from_bits(uint32_t bits) {
  uint32_t fb = (bits >> 9) | 0x3F800000u;
  float f = __uint_as_float(fb) - 1.0f;          // [0, 1)
  float u = fmaxf(f, __FLT_MIN__);               // jnp.finfo(f32).tiny
  float lg = (float)log((double)u);
  return -(float)log((double)(-lg));
}

// ---------------------------------------------------------------------------
// 4-state chain encoding: 0:(p1=0) 1:(p1=1) 2:(p1=2,spec=0) 3:(p1=2,spec=1).
// Step: s = (st==3) ? sB : sA;  st' = (st==1 && s==2) ? 3 : s.
// Map over 4 states packed 2 bits/state in low 8 bits of a u32.
// ---------------------------------------------------------------------------
__device__ __forceinline__ uint32_t comp_map(uint32_t a, uint32_t b) {
  uint32_t r = 0;
#pragma unroll
  for (int st = 0; st < 4; ++st) {
    uint32_t as = (a >> (2 * st)) & 3u;
    uint32_t bs = (b >> (2 * as)) & 3u;
    r |= bs << (2 * st);
  }
  return r;
}

// ---------------------------------------------------------------------------
// K1: per (t,b): key_t = threefry((0,42),(0,t)) [partitionable split], then
// 3 gumbels (element e=3b+j -> y0^y1 of threefry(key_t,(0,e))), argmax over
//   row A (generic):             [LP, LS, LP]
//   row B (state (p2,p1)=(1,2)): [-inf, LB1, LB2]
// Stores u32 = sA | (sB<<4) with AGENT scope. Spread over ALL CUs — this is
// where the heavy ALU (threefry + double-logs) must live (round-4 lesson:
// same work packed into 32 blocks cost ~60 us; here it's <8 us).
// ---------------------------------------------------------------------------
__global__ void k_sab(uint32_t* __restrict__ sab32,
                      float LP, float LS, float LB1, float LB2) {
  int t = blockIdx.x * blockDim.x + threadIdx.x;
  int b = blockIdx.y;
  if (t >= NSTEPS) return;
  uint32_t k0 = 0u, k1 = (uint32_t)t;
  threefry2x32(0u, 42u, k0, k1);                 // key_t
  float g[3];
#pragma unroll
  for (int j = 0; j < 3; ++j) {
    uint32_t x0 = 0u, x1 = (uint32_t)(3 * b + j);
    threefry2x32(k0, k1, x0, x1);
    g[j] = gumbel_from_bits(x0 ^ x1);
  }
  float vA0 = LP + g[0], vA1 = LS + g[1], vA2 = LP + g[2];
  int sA = 0; float m = vA0;
  if (vA1 > m) { m = vA1; sA = 1; }
  if (vA2 > m) { sA = 2; }
  int sB = (LB2 + g[2] > LB1 + g[1]) ? 2 : 1;    // j=0 logit is -inf
  uint32_t v = (uint32_t)(sA | (sB << 4));
  __hip_atomic_store(&sab32[(size_t)b * NT + t], v,
                     __ATOMIC_RELAXED, __HIP_MEMORY_SCOPE_AGENT);
}

// ---------------------------------------------------------------------------
// K2: one block per batch — scan only (no RNG ALU here). Load 8 sab words
// per thread, build 4-state chunk map, Hillis-Steele scan in LDS, replay,
// cooperative AGENT-scope stores of packed m words.
// ---------------------------------------------------------------------------
__global__ void __launch_bounds__(THR) k_scan(uint32_t* __restrict__ sab32,
                                              uint32_t* __restrict__ mword) {
  const int b = blockIdx.x;
  const int tid = threadIdx.x;

  __shared__ uint32_t smap[THR];
  __shared__ uint8_t lds_m[NT];

  // ---- load my SPT sab entries (pack nibbles) ----
  uint32_t packA = 0, packB = 0;
  const uint32_t* src = sab32 + (size_t)b * NT;
#pragma unroll
  for (int k = 0; k < SPT; ++k) {
    int t = tid * SPT + k;
    if (t >= NSTEPS) break;
    uint32_t w = __hip_atomic_load(&src[t], __ATOMIC_RELAXED,
                                   __HIP_MEMORY_SCOPE_AGENT);
    packA |= (w & 0xFu) << (4 * k);
    packB |= ((w >> 4) & 0xFu) << (4 * k);
  }

  // ---- build my chunk map ----
  uint32_t cmap;
  {
    uint32_t st0 = 0, st1 = 1, st2 = 2, st3 = 3;
#pragma unroll
    for (int k = 0; k < SPT; ++k) {
      int t = tid * SPT + k;
      if (t >= NSTEPS) break;
      uint32_t sA = (packA >> (4 * k)) & 0xFu;
      uint32_t sB = (packB >> (4 * k)) & 0xFu;
#define STEP(st) { uint32_t s = (st == 3u) ? sB : sA; st = (st == 1u && s == 2u) ? 3u : s; }
      STEP(st0) STEP(st1) STEP(st2) STEP(st3)
#undef STEP
    }
    cmap = st0 | (st1 << 2) | (st2 << 4) | (st3 << 6);
  }
  smap[tid] = cmap;
  __syncthreads();
  for (int d = 1; d < THR; d <<= 1) {
    uint32_t prev = (tid >= d) ? smap[tid - d] : 0u;
    __syncthreads();
    if (tid >= d) smap[tid] = comp_map(prev, smap[tid]);
    __syncthreads();
  }
  uint32_t st = (tid == 0) ? 1u : ((smap[tid - 1] >> 2) & 3u);

  // ---- replay, write m bytes ----
#pragma unroll
  for (int k = 0; k < SPT; ++k) {
    int t = tid * SPT + k;
    if (t >= NSTEPS) break;
    uint32_t sA = (packA >> (4 * k)) & 0xFu;
    uint32_t sB = (packB >> (4 * k)) & 0xFu;
    uint32_t s = (st == 3u) ? sB : sA;
    st = (st == 1u && s == 2u) ? 3u : s;
    lds_m[t + 1] = (uint8_t)s;
  }
  if (tid == 0) lds_m[0] = 1;
  if (tid == THR - 1) lds_m[NT - 1] = 1;
  __syncthreads();

  const uint32_t* wsrc = (const uint32_t*)lds_m;
  uint32_t* dst = mword + (size_t)b * (NT / 4);
#pragma unroll
  for (int r = 0; r < (NT / 4) / THR; ++r) {
    int w = r * THR + tid;
    __hip_atomic_store(&dst[w], wsrc[w],
                       __ATOMIC_RELAXED, __HIP_MEMORY_SCOPE_AGENT);
  }
}

// ---------------------------------------------------------------------------
// K3: gather out[b,i,t] = x[b,i, m[b,t] + t - 1], float4 stores over t.
// Measured at ~7.06 TB/s combined R+W (= fill-rate ceiling) — untouched.
// ---------------------------------------------------------------------------
__global__ void k_gather(const float* __restrict__ x, uint32_t* __restrict__ mword,
                         float* __restrict__ out) {
  const int QUADS = NB * NI * (NT / 4);          // 16,777,216
  int stride = gridDim.x * blockDim.x;
  for (int q = blockIdx.x * blockDim.x + threadIdx.x; q < QUADS; q += stride) {
    int b   = q >> 19;                           // NI * NT/4 = 2^19
    int rem = q & ((1 << 19) - 1);
    int i   = rem >> 10;                         // NT/4 = 1024
    int t   = (rem & 1023) << 2;
    uint32_t mw = __hip_atomic_load(&mword[((size_t)b << 10) + (t >> 2)],
                                    __ATOMIC_RELAXED, __HIP_MEMORY_SCOPE_AGENT);
    const float* xb = x + (((size_t)b * NI + i) << 12);
    float4 o;
    o.x = xb[(int)( mw        & 0xFFu) + t + 0 - 1];
    o.y = xb[(int)((mw >>  8) & 0xFFu) + t + 1 - 1];
    o.z = xb[(int)((mw >> 16) & 0xFFu) + t + 2 - 1];
    o.w = xb[(int)((mw >> 24) & 0xFFu) + t + 3 - 1];
    *(float4*)(out + (((size_t)b * NI + i) << 12) + t) = o;
  }
}

// ---------------------------------------------------------------------------
extern "C" void kernel_launch(void* const* d_in, const int* in_sizes, int n_in,
                              void* d_out, int out_size, void* d_ws, size_t ws_size,
                              hipStream_t stream) {
  const float* x = (const float*)d_in[0];
  float* out = (float*)d_out;

  uint8_t* ws = (uint8_t*)d_ws;
  uint32_t* sab32 = (uint32_t*)ws;               // 32*4096*4 = 524288 B
  uint32_t* mword = (uint32_t*)(ws + 524288);    // 32*1024*4 = 131072 B

  const double pd = 0.1, sd = 1.0 - 2.0 * 0.1;
  const float pf = (float)pd, sf = (float)sd;
  const float b1 = (float)(sd / (pd + sd));
  const float b2 = (float)(pd / (pd + sd));
  const float LP  = (float)log((double)pf);
  const float LS  = (float)log((double)sf);
  const float LB1 = (float)log((double)b1);
  const float LB2 = (float)log((double)b2);

  dim3 g1((NSTEPS + 255) / 256, NB);
  k_sab<<<g1, 256, 0, stream>>>(sab32, LP, LS, LB1, LB2);
  k_scan<<<NB, THR, 0, stream>>>(sab32, mword);
  k_gather<<<4096, 256, 0, stream>>>(x, mword, out);
}